// Round 3
// baseline (187.774 us; speedup 1.0000x reference)
//
#include <hip/hip_runtime.h>

#define B_   8
#define KB_  16
#define SEQ_ 512
#define HID_ 768

#define NKB  (HID_ / 32)     // 24 k-blocks per row
#define QRB  (B_  * SEQ_ / 16)   // 256 Q row-blocks
#define KRB  (KB_ * SEQ_ / 16)   // 512 K row-blocks

typedef __attribute__((ext_vector_type(4))) _Float16 half4;
typedef __attribute__((ext_vector_type(8))) _Float16 half8;
typedef __attribute__((ext_vector_type(4))) float    floatx4;

// ---------------- prepass: L2-normalize rows -> fp16 in MFMA-fragment-tiled layout ----
// Tile = 16 rows x 32 k = 1KB, stored lane-major: element(row,k) at
// lane = (row&15) | ((k>>3)<<4), idx = k&7, offset = lane*8+idx.
// One 256-thread block per 16-row block.
#define LP 776   // LDS row stride in halves (1552B, 16B-aligned)

__global__ __launch_bounds__(256)
void prep_tile(const float* __restrict__ Q, const float* __restrict__ K,
               _Float16* __restrict__ Qt, _Float16* __restrict__ Kt)
{
    const int rb = blockIdx.x;   // 0..767
    const float* src;
    _Float16*    dst;
    if (rb < QRB) { src = Q + (size_t)rb * 16 * HID_;          dst = Qt + (size_t)rb * NKB * 512; }
    else          { src = K + (size_t)(rb - QRB) * 16 * HID_;  dst = Kt + (size_t)(rb - QRB) * NKB * 512; }

    __shared__ _Float16 Ls[16 * LP];
    const int wave = threadIdx.x >> 6;
    const int lane = threadIdx.x & 63;

#pragma unroll
    for (int rr = 0; rr < 4; ++rr) {
        int row = wave * 4 + rr;
        const float* s = src + (size_t)row * HID_;
        float4 v[3];
        float ss = 0.f;
#pragma unroll
        for (int it = 0; it < 3; ++it) {
            v[it] = *(const float4*)(s + lane * 4 + it * 256);
            ss += v[it].x * v[it].x + v[it].y * v[it].y + v[it].z * v[it].z + v[it].w * v[it].w;
        }
#pragma unroll
        for (int m = 1; m < 64; m <<= 1) ss += __shfl_xor(ss, m, 64);
        float sc = 1.0f / fmaxf(sqrtf(ss), 1e-12f);
#pragma unroll
        for (int it = 0; it < 3; ++it) {
            half4 h = { (_Float16)(v[it].x * sc), (_Float16)(v[it].y * sc),
                        (_Float16)(v[it].z * sc), (_Float16)(v[it].w * sc) };
            *(half4*)(Ls + row * LP + lane * 4 + it * 256) = h;
        }
    }
    __syncthreads();

    // write 24 tiles x 1KB, coalesced (one wave writes one tile per step)
#pragma unroll
    for (int rep = 0; rep < 6; ++rep) {
        int slot = rep * 256 + threadIdx.x;      // 0..1535
        int kb   = slot >> 6;
        int ln   = slot & 63;
        int row  = ln & 15;
        int ko   = kb * 32 + (ln >> 4) * 8;
        half8 h = *(const half8*)(Ls + row * LP + ko);
        *(half8*)(dst + (size_t)kb * 512 + (size_t)ln * 8) = h;
    }
}

// ---------------- phase 1: direct-from-global fragment GEMM + softmax partials ----------
#define BM  128
#define BN  128

__global__ __launch_bounds__(256, 3)
void li_part(const _Float16* __restrict__ Qt, const _Float16* __restrict__ Kt,
             const float* __restrict__ alpha_p, const int* __restrict__ kmask,
             float* __restrict__ Pbuf)
{
    const int st = blockIdx.x >> 2;   // s tile (0..3)
    const int tb = blockIdx.x & 3;    // t tile (0..3)
    const int j  = blockIdx.y;
    const int i  = blockIdx.z;

    const int tid  = threadIdx.x;
    const int lane = tid & 63;
    const int wave = tid >> 6;
    const int quad = lane >> 4;
    const int l16  = lane & 15;
    const int wr   = wave >> 1;   // wave row-half
    const int wc   = wave & 1;    // wave col-half

    __shared__ float pm[2][BM], pl[2][BM], pn[2][BM];

    const float araw  = *alpha_p;
    const float alpha = araw >= 0.f ? araw : 0.01f * araw;   // leaky_relu

    // fragment base pointers (row-block-tiled layout)
    const _Float16* Abase = Qt + ((size_t)(i * 32 + st * 8 + wr * 4) * NKB) * 512 + (size_t)lane * 8;
    const _Float16* Bbase = Kt + ((size_t)(j * 32 + tb * 8 + wc * 4) * NKB) * 512 + (size_t)lane * 8;

    floatx4 acc[4][4];
#pragma unroll
    for (int rt = 0; rt < 4; ++rt)
#pragma unroll
        for (int ct = 0; ct < 4; ++ct)
            acc[rt][ct] = (floatx4){0.f, 0.f, 0.f, 0.f};

    for (int kb = 0; kb < NKB; ++kb) {
        half8 af[4], bf[4];
#pragma unroll
        for (int rt = 0; rt < 4; ++rt)
            af[rt] = *(const half8*)(Abase + ((size_t)rt * NKB + kb) * 512);
#pragma unroll
        for (int ct = 0; ct < 4; ++ct)
            bf[ct] = *(const half8*)(Bbase + ((size_t)ct * NKB + kb) * 512);
#pragma unroll
        for (int rt = 0; rt < 4; ++rt)
#pragma unroll
            for (int ct = 0; ct < 4; ++ct)
                acc[rt][ct] = __builtin_amdgcn_mfma_f32_16x16x32_f16(af[rt], bf[ct], acc[rt][ct], 0, 0, 0);
    }

    // ---- epilogue: per-row softmax partial (m, l, n) over this 128-col t-tile ----
    const int* km = kmask + j * SEQ_ + tb * BN;
    int kmv[4]; float tgf[4];
#pragma unroll
    for (int ct = 0; ct < 4; ++ct) {
        int t_loc = wc * 64 + ct * 16 + l16;
        kmv[ct] = km[t_loc];
        tgf[ct] = (float)(tb * BN + t_loc);
    }
#pragma unroll
    for (int rt = 0; rt < 4; ++rt) {
#pragma unroll
        for (int r = 0; r < 4; ++r) {
            float sgf = (float)(st * BM + wr * 64 + rt * 16 + quad * 4 + r);
            float cv[4], w[4];
            float tmax = -INFINITY;
#pragma unroll
            for (int ct = 0; ct < 4; ++ct) {
                cv[ct] = acc[rt][ct][r];
                float d = fabsf(sgf - tgf[ct]);
                w[ct] = kmv[ct] ? cv[ct] * __expf(-alpha * d) : -INFINITY;
                tmax = fmaxf(tmax, w[ct]);
            }
#pragma unroll
            for (int msk = 1; msk < 16; msk <<= 1)
                tmax = fmaxf(tmax, __shfl_xor(tmax, msk, 64));
            float ps = 0.f, ns = 0.f;
            if (tmax != -INFINITY) {   // quad-uniform; shuffles stay within quad
#pragma unroll
                for (int ct = 0; ct < 4; ++ct) {
                    float e = __expf(w[ct] - tmax);   // exp(-inf)=0 handles masked cols
                    ps += e;
                    ns += e * cv[ct];
                }
#pragma unroll
                for (int msk = 1; msk < 16; msk <<= 1) {
                    ps += __shfl_xor(ps, msk, 64);
                    ns += __shfl_xor(ns, msk, 64);
                }
            }
            if (l16 == 0) {
                int rloc = wr * 64 + rt * 16 + quad * 4 + r;
                pm[wc][rloc] = tmax;
                pl[wc][rloc] = ps;
                pn[wc][rloc] = ns;
            }
        }
    }
    __syncthreads();

    // merge the two col-half waves; write one (m,l,n) partial per row per t-tile
    if (tid < BM) {
        float m0 = pm[0][tid], m1 = pm[1][tid];
        float M = fmaxf(m0, m1);
        float l = 0.f, n = 0.f;
        if (M != -INFINITY) {
            float e0 = __expf(m0 - M), e1 = __expf(m1 - M);
            l = pl[0][tid] * e0 + pl[1][tid] * e1;
            n = pn[0][tid] * e0 + pn[1][tid] * e1;
        }
        size_t base = (((size_t)(i * KB_ + j) * SEQ_) + st * BM + tid) * 12 + tb * 3;
        Pbuf[base]     = M;
        Pbuf[base + 1] = l;
        Pbuf[base + 2] = n;
    }
}

// ---------------- phase 2: merge t-tile partials, apply q_mask, reduce over s ----------
__global__ __launch_bounds__(256)
void li_reduce(const float* __restrict__ Pbuf, const int* __restrict__ qmask,
               float* __restrict__ out)
{
    const int ij = blockIdx.x;
    const int i  = ij >> 4;           // KB_ == 16
    const int tid = threadIdx.x;
    __shared__ float red[4];

    float sum = 0.f;
#pragma unroll
    for (int rep = 0; rep < 2; ++rep) {
        int s = tid + rep * 256;
        const float4* p = (const float4*)(Pbuf + ((size_t)ij * SEQ_ + s) * 12);
        float4 a = p[0], b = p[1], c = p[2];
        // layout per row: [m0,l0,n0, m1,l1,n1, m2,l2,n2, m3,l3,n3]
        float M = fmaxf(fmaxf(a.x, a.w), fmaxf(b.z, c.y));
        float sc = 0.f;
        if (M != -INFINITY) {
            float e0 = __expf(a.x - M), e1 = __expf(a.w - M);
            float e2 = __expf(b.z - M), e3 = __expf(c.y - M);
            float l = a.y * e0 + b.x * e1 + b.w * e2 + c.z * e3;
            float n = a.z * e0 + b.y * e1 + c.x * e2 + c.w * e3;
            sc = (l > 0.f) ? n / l : 0.f;
        }
        if (qmask[i * SEQ_ + s] == 0) sc = 0.f;
        sum += sc;
    }
#pragma unroll
    for (int m = 1; m < 64; m <<= 1) sum += __shfl_xor(sum, m, 64);
    if ((tid & 63) == 0) red[tid >> 6] = sum;
    __syncthreads();
    if (tid == 0) out[ij] = red[0] + red[1] + red[2] + red[3];
}

extern "C" void kernel_launch(void* const* d_in, const int* in_sizes, int n_in,
                              void* d_out, int out_size, void* d_ws, size_t ws_size,
                              hipStream_t stream)
{
    const float* Q       = (const float*)d_in[0];
    const float* K       = (const float*)d_in[1];
    const float* alpha_p = (const float*)d_in[2];
    const int*   qmask   = (const int*)d_in[3];
    const int*   kmask   = (const int*)d_in[4];
    float*       out     = (float*)d_out;

    char* ws = (char*)d_ws;
    _Float16* Qt   = (_Float16*)ws;
    _Float16* Kt   = (_Float16*)(ws + (size_t)B_ * SEQ_ * HID_ * 2);
    float*    Pbuf = (float*)   (ws + (size_t)(B_ + KB_) * SEQ_ * HID_ * 2);

    prep_tile<<<QRB + KRB, 256, 0, stream>>>(Q, K, Qt, Kt);

    dim3 grid(16, KB_, B_);   // (st*4+tb, j, i)
    li_part<<<grid, 256, 0, stream>>>(Qt, Kt, alpha_p, kmask, Pbuf);

    li_reduce<<<B_ * KB_, 256, 0, stream>>>(Pbuf, qmask, out);
}

// Round 4
// 141.073 us; speedup vs baseline: 1.3310x; 1.3310x over previous
//
#include <hip/hip_runtime.h>
#include <stdint.h>

#define B_   8
#define KB_  16
#define SEQ_ 512
#define HID_ 768

#define NKB  (HID_ / 32)         // 24 k-blocks (32 halves each) per row
#define QRB  (B_  * SEQ_ / 16)   // 256 Q row-blocks of 16 rows
#define KRB  (KB_ * SEQ_ / 16)   // 512 K row-blocks

typedef __attribute__((ext_vector_type(4))) _Float16 half4;
typedef __attribute__((ext_vector_type(8))) _Float16 half8;
typedef __attribute__((ext_vector_type(4))) float    floatx4;

#define GLOBAL_AS __attribute__((address_space(1)))
#define LDS_AS    __attribute__((address_space(3)))

// async 16B/lane global->LDS copy: LDS dest = base + lane*16 (wave-uniform base)
static __device__ __forceinline__ void async_tile16(const _Float16* g, _Float16* l)
{
    __builtin_amdgcn_global_load_lds((const GLOBAL_AS uint32_t*)g,
                                     (LDS_AS uint32_t*)l, 16, 0, 0);
}

// ---------------- prepass: L2-normalize rows -> fp16 in MFMA-fragment-tiled layout ----
// Tile = 16 rows x 32 k = 1KB, lane-major: element(row,k) at lane = row | ((k>>3)<<4),
// idx = k&7. One 256-thread block per 16-row block.
#define LP 776   // LDS row stride in halves

__global__ __launch_bounds__(256)
void prep_tile(const float* __restrict__ Q, const float* __restrict__ K,
               _Float16* __restrict__ Qt, _Float16* __restrict__ Kt)
{
    const int rb = blockIdx.x;   // 0..767
    const float* src;
    _Float16*    dst;
    if (rb < QRB) { src = Q + (size_t)rb * 16 * HID_;          dst = Qt + (size_t)rb * NKB * 512; }
    else          { src = K + (size_t)(rb - QRB) * 16 * HID_;  dst = Kt + (size_t)(rb - QRB) * NKB * 512; }

    __shared__ _Float16 Ls[16 * LP];
    const int wave = threadIdx.x >> 6;
    const int lane = threadIdx.x & 63;

#pragma unroll
    for (int rr = 0; rr < 4; ++rr) {
        int row = wave * 4 + rr;
        const float* s = src + (size_t)row * HID_;
        float4 v[3];
        float ss = 0.f;
#pragma unroll
        for (int it = 0; it < 3; ++it) {
            v[it] = *(const float4*)(s + lane * 4 + it * 256);
            ss += v[it].x * v[it].x + v[it].y * v[it].y + v[it].z * v[it].z + v[it].w * v[it].w;
        }
#pragma unroll
        for (int m = 1; m < 64; m <<= 1) ss += __shfl_xor(ss, m, 64);
        float sc = 1.0f / fmaxf(sqrtf(ss), 1e-12f);
#pragma unroll
        for (int it = 0; it < 3; ++it) {
            half4 h = { (_Float16)(v[it].x * sc), (_Float16)(v[it].y * sc),
                        (_Float16)(v[it].z * sc), (_Float16)(v[it].w * sc) };
            *(half4*)(Ls + row * LP + lane * 4 + it * 256) = h;
        }
    }
    __syncthreads();

#pragma unroll
    for (int rep = 0; rep < 6; ++rep) {
        int slot = rep * 256 + threadIdx.x;      // 0..1535 = 24 tiles x 64 lanes
        int kb   = slot >> 6;
        int ln   = slot & 63;
        int row  = ln & 15;
        int ko   = kb * 32 + (ln >> 4) * 8;
        half8 h = *(const half8*)(Ls + row * LP + ko);
        *(half8*)(dst + (size_t)kb * 512 + (size_t)ln * 8) = h;
    }
}

// ---------------- phase 1: LDS-staged GEMM (128x256 tile) + sum-softmax partials ------
// grid: x = st*2 + tb (8), y = j (16), z = i (8); 512 threads = 8 waves of 64x64.
__global__ __launch_bounds__(512, 4)
void li_part(const _Float16* __restrict__ Qt, const _Float16* __restrict__ Kt,
             const float* __restrict__ alpha_p, const int* __restrict__ kmask,
             float* __restrict__ Pbuf)
{
    const int st = blockIdx.x >> 1;   // s tile (0..3), 128 rows
    const int tb = blockIdx.x & 1;    // t half (0..1), 256 cols
    const int j  = blockIdx.y;
    const int i  = blockIdx.z;

    const int tid  = threadIdx.x;
    const int lane = tid & 63;
    const int wave = tid >> 6;        // 0..7
    const int quad = lane >> 4;
    const int l16  = lane & 15;
    const int wr   = wave >> 2;       // row half (0/1): rows wr*64..+63
    const int wc   = wave & 3;        // col quarter (0..3): cols wc*64..+63

    // double-buffered staging: 24 tiles (8 Q + 16 K) x 512 halves per buffer
    __shared__ _Float16 Sbuf[2][24 * 512];
    __shared__ float lred[4][128], nred[4][128];

    const float araw  = *alpha_p;
    const float alpha = araw >= 0.f ? araw : 0.01f * araw;   // leaky_relu

    const int qbase = i * 32 + st * 8;        // Q row-block index
    const int kbase = j * 32 + tb * 16;       // K row-block index

    // staging assignment: this wave stages tiles wave*3 .. wave*3+2
    const _Float16* gsrc[3];
    _Float16*       ldst0[3];
#pragma unroll
    for (int q = 0; q < 3; ++q) {
        int t   = wave * 3 + q;
        int rbg = (t < 8) ? (qbase + t) : (kbase + (t - 8));
        const _Float16* base = (t < 8) ? Qt : Kt;
        gsrc[q]  = base + (size_t)rbg * NKB * 512 + (size_t)lane * 8;
        ldst0[q] = &Sbuf[0][t * 512];
    }

    floatx4 acc[4][4];
#pragma unroll
    for (int rt = 0; rt < 4; ++rt)
#pragma unroll
        for (int ct = 0; ct < 4; ++ct)
            acc[rt][ct] = (floatx4){0.f, 0.f, 0.f, 0.f};

    // stage kb=0 into buffer 0
#pragma unroll
    for (int q = 0; q < 3; ++q)
        async_tile16(gsrc[q], ldst0[q]);

    for (int kb = 0; kb < NKB; ++kb) {
        const int b = kb & 1;
        __syncthreads();   // drains own staging (vmcnt) + fences prior reads of buf b^1
        if (kb + 1 < NKB) {
#pragma unroll
            for (int q = 0; q < 3; ++q)
                async_tile16(gsrc[q] + (size_t)(kb + 1) * 512, ldst0[q] + (b ^ 1) * 24 * 512);
        }
        const _Float16* Qs = &Sbuf[b][0];
        const _Float16* Ks = &Sbuf[b][8 * 512];
        half8 af[4], bf[4];
#pragma unroll
        for (int rt = 0; rt < 4; ++rt)
            af[rt] = *(const half8*)(Qs + (wr * 4 + rt) * 512 + lane * 8);
#pragma unroll
        for (int ct = 0; ct < 4; ++ct)
            bf[ct] = *(const half8*)(Ks + (wc * 4 + ct) * 512 + lane * 8);
#pragma unroll
        for (int rt = 0; rt < 4; ++rt)
#pragma unroll
            for (int ct = 0; ct < 4; ++ct)
                acc[rt][ct] = __builtin_amdgcn_mfma_f32_16x16x32_f16(af[rt], bf[ct], acc[rt][ct], 0, 0, 0);
    }

    // ---- epilogue: sum-softmax partials (logits in [-1,1] -> no max needed) ----
    const int* km = kmask + j * SEQ_ + tb * 256;
    int kmv[4]; float tgf[4];
#pragma unroll
    for (int ct = 0; ct < 4; ++ct) {
        int t_loc = wc * 64 + ct * 16 + l16;
        kmv[ct] = km[t_loc];
        tgf[ct] = (float)(tb * 256 + t_loc);
    }
#pragma unroll
    for (int rt = 0; rt < 4; ++rt) {
#pragma unroll
        for (int r = 0; r < 4; ++r) {
            float sgf = (float)(st * 128 + wr * 64 + rt * 16 + quad * 4 + r);
            float ps = 0.f, ns = 0.f;
#pragma unroll
            for (int ct = 0; ct < 4; ++ct) {
                float cv = acc[rt][ct][r];
                float e  = kmv[ct] ? __expf(cv * __expf(-alpha * fabsf(sgf - tgf[ct]))) : 0.f;
                ps += e;
                ns += e * cv;
            }
#pragma unroll
            for (int msk = 1; msk < 16; msk <<= 1) {
                ps += __shfl_xor(ps, msk, 64);
                ns += __shfl_xor(ns, msk, 64);
            }
            if (l16 == 0) {
                int rloc = wr * 64 + rt * 16 + quad * 4 + r;
                lred[wc][rloc] = ps;
                nred[wc][rloc] = ns;
            }
        }
    }
    __syncthreads();

    // merge 4 col-quarters; one (l,n) per row per t-half
    if (tid < 128) {
        float l = lred[0][tid] + lred[1][tid] + lred[2][tid] + lred[3][tid];
        float n = nred[0][tid] + nred[1][tid] + nred[2][tid] + nred[3][tid];
        size_t base = (((size_t)(i * KB_ + j) * SEQ_) + st * 128 + tid) * 4 + tb * 2;
        Pbuf[base]     = l;
        Pbuf[base + 1] = n;
    }
}

// ---------------- phase 2: merge t-halves, apply q_mask, reduce over s ----------------
__global__ __launch_bounds__(256)
void li_reduce(const float* __restrict__ Pbuf, const int* __restrict__ qmask,
               float* __restrict__ out)
{
    const int ij = blockIdx.x;
    const int i  = ij >> 4;           // KB_ == 16
    const int tid = threadIdx.x;
    __shared__ float red[4];

    float sum = 0.f;
#pragma unroll
    for (int rep = 0; rep < 2; ++rep) {
        int s = tid + rep * 256;
        float4 a = *(const float4*)(Pbuf + ((size_t)ij * SEQ_ + s) * 4);
        float l = a.x + a.z;
        float n = a.y + a.w;
        float sc = (l > 0.f) ? n / l : 0.f;
        if (qmask[i * SEQ_ + s] == 0) sc = 0.f;
        sum += sc;
    }
#pragma unroll
    for (int m = 1; m < 64; m <<= 1) sum += __shfl_xor(sum, m, 64);
    if ((tid & 63) == 0) red[tid >> 6] = sum;
    __syncthreads();
    if (tid == 0) out[ij] = red[0] + red[1] + red[2] + red[3];
}

extern "C" void kernel_launch(void* const* d_in, const int* in_sizes, int n_in,
                              void* d_out, int out_size, void* d_ws, size_t ws_size,
                              hipStream_t stream)
{
    const float* Q       = (const float*)d_in[0];
    const float* K       = (const float*)d_in[1];
    const float* alpha_p = (const float*)d_in[2];
    const int*   qmask   = (const int*)d_in[3];
    const int*   kmask   = (const int*)d_in[4];
    float*       out     = (float*)d_out;

    char* ws = (char*)d_ws;
    _Float16* Qt   = (_Float16*)ws;
    _Float16* Kt   = (_Float16*)(ws + (size_t)B_ * SEQ_ * HID_ * 2);
    float*    Pbuf = (float*)   (ws + (size_t)(B_ + KB_) * SEQ_ * HID_ * 2);

    prep_tile<<<QRB + KRB, 256, 0, stream>>>(Q, K, Qt, Kt);

    dim3 grid(8, KB_, B_);   // (st*2+tb, j, i)
    li_part<<<grid, 512, 0, stream>>>(Qt, Kt, alpha_p, kmask, Pbuf);

    li_reduce<<<B_ * KB_, 256, 0, stream>>>(Pbuf, qmask, out);
}